// Round 7
// baseline (120.923 us; speedup 1.0000x reference)
//
#include <hip/hip_runtime.h>
#include <hip/hip_bf16.h>

// Conv2d 3x3 s1 p1, NCHW/OIHW fp32 -> fp32. bf16 implicit GEMM with
// conv-aware LDS reuse. R3: bank-conflict-free LDS layouts via staged-chunk
// permutation (lk-outermost), keeping global_load_lds linear dests.

#define C_IN   128
#define K_OUT  256
#define HW     56
#define IMG    3136
#define NBATCH 32
#define SPATIAL 100352
#define PW     58
#define PADTOT (NBATCH*PW*PW*C_IN)
#define KTOT   1152

typedef __bf16 bf16x8 __attribute__((ext_vector_type(8)));
typedef float  f32x4  __attribute__((ext_vector_type(4)));
typedef unsigned short ushort8 __attribute__((ext_vector_type(8)));

__device__ inline unsigned short f2bf(float f) {
    unsigned int u = __builtin_bit_cast(unsigned int, f);
    u += ((u >> 16) & 1u) + 0x7FFFu;   // RNE
    return (unsigned short)(u >> 16);
}

__device__ __forceinline__ void gl2lds16(const unsigned short* g, unsigned short* l) {
    __builtin_amdgcn_global_load_lds(
        (const __attribute__((address_space(1))) unsigned int*)g,
        (__attribute__((address_space(3))) unsigned int*)l, 16, 0, 0);
}

// ---- prep A: NCHW fp32 -> padded NHWC bf16 [n][py 0..57][px 0..57][c] ----
__global__ void prep_input(const float* __restrict__ inp,
                           unsigned short* __restrict__ dst) {
    __shared__ unsigned short tile[C_IN * 57];   // [c][x], stride 57
    int n = blockIdx.x / PW, py = blockIdx.x % PW;
    ushort8* d8 = (ushort8*)(dst + (size_t)blockIdx.x * (PW * C_IN));
    if (py == 0 || py == PW - 1) {
        for (int i = threadIdx.x; i < PW * C_IN / 8; i += 256) d8[i] = (ushort8)0;
        return;
    }
    const float* src = inp + (size_t)n * C_IN * IMG + (py - 1) * HW;
    for (int i = threadIdx.x; i < C_IN * HW; i += 256) {
        int c = i / HW, x = i - c * HW;          // coalesced read along x
        tile[c * 57 + x] = f2bf(src[c * IMG + x]);
    }
    __syncthreads();
    for (int i = threadIdx.x; i < PW * C_IN / 8; i += 256) {   // 928 chunks
        int px = i >> 4, c0 = (i & 15) * 8;
        ushort8 v = (ushort8)0;
        if (px >= 1 && px <= HW) {
#pragma unroll
            for (int e = 0; e < 8; ++e) v[e] = tile[(c0 + e) * 57 + (px - 1)];
        }
        d8[i] = v;
    }
}

// ---- prep B: OIHW fp32 -> [ko][rs][c] bf16 ----
__global__ void prep_weights(const float* __restrict__ w,
                             unsigned short* __restrict__ dst) {
    int idx = blockIdx.x * 256 + threadIdx.x;
    int ko = idx / KTOT, rem = idx - ko * KTOT;
    int rs = rem >> 7, c = rem & 127;
    dst[idx] = f2bf(w[(ko * C_IN + c) * 9 + rs]);
}

// ---- main conv ----
// LDS (ushort idx): wslot0 [0,24576) wslot1 [24576,49152)
//                   islot0 [49152,61440) islot1 [61440,73728)
// wslot chunk layout (16B units): [3 s][4 cc][256 ko]  -> conflict-free A reads
// islot chunk layout:             [4 cc][6 t][58 X]    -> conflict-free B reads
__global__ __launch_bounds__(512, 2) void conv_mfma(
        const unsigned short* __restrict__ In,
        const unsigned short* __restrict__ Wt,
        const float* __restrict__ bias,
        float* __restrict__ out) {
    __shared__ unsigned short smem[73728];

    const int tid = threadIdx.x;
    const int lane = tid & 63, wv = tid >> 6;
    const int l15 = lane & 15, lk = lane >> 4;
    const int blk = blockIdx.x;
    const int n = blk / 14, rb = (blk % 14) * 4;   // first image row of block

    const int wko = (wv & 3) * 64;                 // wave ko base (local)
    const int wpx = (wv >> 2) * 112;               // wave px base (local)
    const int albase = lk * 4096 + (wko + l15) * 16;   // A lane byte offset

    int rowoff[7];                                 // B lane byte offsets
#pragma unroll
    for (int nf = 0; nf < 7; ++nf) {
        int p = wpx + nf * 16 + l15;               // local pixel 0..223
        int yl = p / 56, x = p - yl * 56;
        rowoff[nf] = lk * 5568 + (yl * 58 + x) * 16;
    }

    f32x4 acc[4][7];
#pragma unroll
    for (int m = 0; m < 4; ++m)
#pragma unroll
        for (int nf = 0; nf < 7; ++nf) acc[m][nf] = (f32x4)0.0f;

#define STAGE_W(PHN, RN, CQN) do {                                          \
    _Pragma("unroll")                                                       \
    for (int li = 0; li < 6; ++li) {                                        \
        int chunk = li * 512 + tid;                                         \
        int s_ = chunk >> 10, rem_ = chunk & 1023;                          \
        int cc_ = rem_ >> 8, ko_ = rem_ & 255;                              \
        gl2lds16(Wt + ko_ * KTOT + ((RN) * 3 + s_) * 128 + (CQN) * 32 + cc_ * 8, \
                 &smem[((PHN) & 1) * 24576 + chunk * 8]);                   \
    } } while (0)

#define STAGE_I(CQN, R_) do {                                               \
    int chunk = (R_) * 512 + tid;                                           \
    int ch2 = chunk < 1392 ? chunk : 0;                                     \
    int cc_ = ch2 / 348, rem_ = ch2 - cc_ * 348;                            \
    int t_ = rem_ / 58, X_ = rem_ - t_ * 58;                                \
    gl2lds16(In + (((n * 58 + rb + t_) * 58 + X_) * 128) + (CQN) * 32 + cc_ * 8, \
             &smem[49152 + ((CQN) & 1) * 12288 + chunk * 8]);               \
} while (0)

    // prologue: weights for phase 0, input for c-quarter 0
    STAGE_W(0, 0, 0);
    STAGE_I(0, 0); STAGE_I(0, 1); STAGE_I(0, 2);

#define PHASE(PH) do {                                                      \
    constexpr int cq_ = (PH) / 3, r_ = (PH) % 3;                            \
    if ((PH) < 11) { STAGE_W((PH) + 1, ((PH) + 1) % 3, ((PH) + 1) / 3); }   \
    if (cq_ < 3)   { STAGE_I(cq_ + 1, r_); }                                \
    asm volatile("s_waitcnt vmcnt(%0)"                                      \
                 :: "i"((PH) < 9 ? 7 : ((PH) < 11 ? 6 : 0)) : "memory");    \
    __builtin_amdgcn_s_barrier();                                           \
    { const char* wb = (const char*)smem + ((PH) & 1) * 49152;              \
      const char* ib = (const char*)smem + 98304 + (cq_ & 1) * 24576;       \
      __builtin_amdgcn_s_setprio(1);                                        \
      _Pragma("unroll")                                                     \
      for (int s = 0; s < 3; ++s) {                                         \
          bf16x8 a[4], b[7];                                                \
          _Pragma("unroll")                                                 \
          for (int m = 0; m < 4; ++m)                                       \
              a[m] = *(const bf16x8*)(wb + albase + s * 16384 + m * 256);   \
          _Pragma("unroll")                                                 \
          for (int nf = 0; nf < 7; ++nf)                                    \
              b[nf] = *(const bf16x8*)(ib + rowoff[nf] + (r_ * 58 + s) * 16); \
          _Pragma("unroll")                                                 \
          for (int m = 0; m < 4; ++m)                                       \
              _Pragma("unroll")                                             \
              for (int nf = 0; nf < 7; ++nf)                                \
                  acc[m][nf] = __builtin_amdgcn_mfma_f32_16x16x32_bf16(     \
                      a[m], b[nf], acc[m][nf], 0, 0, 0);                    \
      }                                                                     \
      __builtin_amdgcn_s_setprio(0);                                        \
    }                                                                       \
    __builtin_amdgcn_s_barrier();                                           \
} while (0)

    PHASE(0);  PHASE(1);  PHASE(2);  PHASE(3);
    PHASE(4);  PHASE(5);  PHASE(6);  PHASE(7);
    PHASE(8);  PHASE(9);  PHASE(10); PHASE(11);

#undef PHASE
#undef STAGE_I
#undef STAGE_W

    // epilogue: D col = l15 (pixel), row = lk*4 + j (ko)
    const int sp0 = rb * 56 + wpx;                 // block pixel base in image
#pragma unroll
    for (int m = 0; m < 4; ++m) {
        int kb = wko + m * 16 + lk * 4;            // absolute ko (block covers all 256)
        f32x4 bs = *(const f32x4*)(bias + kb);
#pragma unroll
        for (int nf = 0; nf < 7; ++nf) {
            float* ob = out + ((size_t)(n * K_OUT + kb) * IMG) + sp0 + nf * 16 + l15;
#pragma unroll
            for (int j = 0; j < 4; ++j)
                ob[(size_t)j * IMG] = acc[m][nf][j] + bs[j];
        }
    }
}

// ---- fallback (only if ws too small): naive fp32 direct conv ----
__global__ void conv_naive(const float* __restrict__ inp,
                           const float* __restrict__ ker,
                           const float* __restrict__ bias,
                           float* __restrict__ out, int total) {
    int o = blockIdx.x * blockDim.x + threadIdx.x;
    if (o >= total) return;
    int x = o % HW, y = (o / HW) % HW, ko = (o / IMG) % K_OUT, n = o / (IMG * K_OUT);
    float acc = bias[ko];
    for (int c = 0; c < C_IN; ++c)
        for (int r = 0; r < 3; ++r) {
            int iy = y + r - 1; if ((unsigned)iy >= HW) continue;
            for (int s = 0; s < 3; ++s) {
                int ix = x + s - 1; if ((unsigned)ix >= HW) continue;
                acc += inp[((n * C_IN + c) * HW + iy) * HW + ix]
                     * ker[((ko * C_IN + c) * 3 + r) * 3 + s];
            }
        }
    out[o] = acc;
}

extern "C" void kernel_launch(void* const* d_in, const int* in_sizes, int n_in,
                              void* d_out, int out_size, void* d_ws, size_t ws_size,
                              hipStream_t stream) {
    const float* inp  = (const float*)d_in[0];
    const float* ker  = (const float*)d_in[1];
    const float* bias = (const float*)d_in[2];
    float* out = (float*)d_out;

    const size_t need = (size_t)PADTOT * 2 + (size_t)K_OUT * KTOT * 2;
    if (ws_size < need) {
        int total = NBATCH * K_OUT * IMG;
        conv_naive<<<(total + 255) / 256, 256, 0, stream>>>(inp, ker, bias, out, total);
        return;
    }

    unsigned short* inb = (unsigned short*)d_ws;
    unsigned short* wtb = inb + (size_t)PADTOT;

    prep_input<<<NBATCH * PW, 256, 0, stream>>>(inp, inb);
    prep_weights<<<(K_OUT * KTOT) / 256, 256, 0, stream>>>(ker, wtb);

    conv_mfma<<<448, 512, 0, stream>>>(inb, wtb, bias, out);
}

// Round 8
// 85.540 us; speedup vs baseline: 1.4136x; 1.4136x over previous
//
#include <hip/hip_runtime.h>
#include <hip/hip_bf16.h>

// Conv2d 3x3 s1 p1, NCHW/OIHW fp32 -> fp32. bf16 implicit GEMM with
// conv-aware LDS reuse. R7: workspace laid out EXACTLY as the LDS wants it
// -> global_load_lds is a linear slab copy (coalesced source) AND the
// conflict-free read layout ([s][cc][ko] weights, [cc][t][X] input).

#define C_IN   128
#define K_OUT  256
#define HW     56
#define IMG    3136
#define NBATCH 32
#define PW     58
#define PLANE  3364                  // 58*58 chunks per (plane,n)
#define PADTOT (16*NBATCH*PLANE*8)   // input ws ushorts (= 32*58*58*128)
#define KTOT   1152

typedef __bf16 bf16x8 __attribute__((ext_vector_type(8)));
typedef float  f32x4  __attribute__((ext_vector_type(4)));
typedef unsigned short ushort8 __attribute__((ext_vector_type(8)));

__device__ inline unsigned short f2bf(float f) {
    unsigned int u = __builtin_bit_cast(unsigned int, f);
    u += ((u >> 16) & 1u) + 0x7FFFu;   // RNE
    return (unsigned short)(u >> 16);
}

__device__ __forceinline__ void gl2lds16(const unsigned short* g, unsigned short* l) {
    __builtin_amdgcn_global_load_lds(
        (const __attribute__((address_space(1))) unsigned int*)g,
        (__attribute__((address_space(3))) unsigned int*)l, 16, 0, 0);
}

// ---- prep A: NCHW fp32 -> 16 channel-planes [seg=c/8][n][py][X][8c] bf16 ----
__global__ void prep_input(const float* __restrict__ inp,
                           unsigned short* __restrict__ dst) {
    __shared__ unsigned short tile[C_IN * 57];   // [c][x], stride 57
    int n = blockIdx.x / PW, py = blockIdx.x % PW;
    ushort8* d8 = (ushort8*)dst;
    const bool border = (py == 0 || py == PW - 1);
    if (!border) {
        const float* src = inp + (size_t)n * C_IN * IMG + (py - 1) * HW;
        for (int i = threadIdx.x; i < C_IN * HW; i += 256) {
            int c = i / HW, x = i - c * HW;      // coalesced read along x
            tile[c * 57 + x] = f2bf(src[c * IMG + x]);
        }
        __syncthreads();
    }
    for (int i = threadIdx.x; i < 16 * PW; i += 256) {   // 928 chunks
        int seg = i / PW, X = i - seg * PW;
        ushort8 v = (ushort8)0;
        if (!border && X >= 1 && X <= HW) {
#pragma unroll
            for (int e = 0; e < 8; ++e) v[e] = tile[(seg * 8 + e) * 57 + (X - 1)];
        }
        d8[((seg * NBATCH + n) * PW + py) * PW + X] = v;
    }
}

// ---- prep B: OIHW fp32 -> 12 panels [p=cq*3+r][s][cc][ko][8c] bf16 ----
__global__ void prep_weights(const float* __restrict__ w,
                             unsigned short* __restrict__ dst) {
    int idx = blockIdx.x * 256 + threadIdx.x;    // 0..294911
    int chunk = idx >> 3, e = idx & 7;
    int p = chunk / 3072, rem = chunk - p * 3072;
    int s = rem >> 10, rem2 = rem & 1023;
    int cc = rem2 >> 8, ko = rem2 & 255;
    int cq = p / 3, r = p - 3 * cq;
    int c = cq * 32 + cc * 8 + e;
    dst[idx] = f2bf(w[(ko * C_IN + c) * 9 + r * 3 + s]);
}

// ---- main conv ----
// LDS (ushort idx): wslot0 [0,24576) wslot1 [24576,49152)
//                   islot0 [49152,61440) islot1 [61440,73728)
// wslot chunks (16B): [3 s][4 cc][256 ko]  islot chunks: [4 cc][6 t][58 X]
// Both slabs are copied linearly from identically-laid-out global ws.
__global__ __launch_bounds__(512, 2) void conv_mfma(
        const unsigned short* __restrict__ In,
        const unsigned short* __restrict__ Wt,
        const float* __restrict__ bias,
        float* __restrict__ out) {
    __shared__ unsigned short smem[73728];

    const int tid = threadIdx.x;
    const int lane = tid & 63, wv = tid >> 6;
    const int l15 = lane & 15, lk = lane >> 4;
    const int blk = blockIdx.x;
    const int n = blk / 14, rb = (blk % 14) * 4;   // first image row of block
    const int nb = n * PLANE + rb * PW;            // chunk offset within a plane

    const int wko = (wv & 3) * 64;                 // wave ko base
    const int wpx = (wv >> 2) * 112;               // wave px base (local)
    const int albase = lk * 4096 + (wko + l15) * 16;   // A lane byte offset

    int rowoff[7];                                 // B lane byte offsets
#pragma unroll
    for (int nf = 0; nf < 7; ++nf) {
        int p = wpx + nf * 16 + l15;               // local pixel 0..223
        int yl = p / 56, x = p - yl * 56;
        rowoff[nf] = lk * 5568 + (yl * 58 + x) * 16;
    }

    f32x4 acc[4][7];
#pragma unroll
    for (int m = 0; m < 4; ++m)
#pragma unroll
        for (int nf = 0; nf < 7; ++nf) acc[m][nf] = (f32x4)0.0f;

#define STAGE_W(PHN) do {                                                   \
    _Pragma("unroll")                                                       \
    for (int li = 0; li < 6; ++li) {                                        \
        int chunk = li * 512 + tid;                                         \
        gl2lds16(Wt + (PHN) * 24576 + chunk * 8,                            \
                 &smem[((PHN) & 1) * 24576 + chunk * 8]);                   \
    } } while (0)

#define STAGE_I(CQN, R_) do {                                               \
    int chunk = (R_) * 512 + tid;                                           \
    int ch2 = chunk < 1392 ? chunk : 0;                                     \
    int cc_ = ch2 / 348, rem_ = ch2 - cc_ * 348;                            \
    gl2lds16(In + (((CQN) * 4 + cc_) * (NBATCH * PLANE) + nb + rem_) * 8,   \
             &smem[49152 + ((CQN) & 1) * 12288 + chunk * 8]);               \
} while (0)

    // prologue: weights panel 0, input c-quarter 0
    STAGE_W(0);
    STAGE_I(0, 0); STAGE_I(0, 1); STAGE_I(0, 2);

#define PHASE(PH) do {                                                      \
    constexpr int cq_ = (PH) / 3, r_ = (PH) % 3;                            \
    if ((PH) < 11) { STAGE_W((PH) + 1); }                                   \
    if (cq_ < 3)   { STAGE_I(cq_ + 1, r_); }                                \
    asm volatile("s_waitcnt vmcnt(%0)"                                      \
                 :: "i"((PH) < 9 ? 7 : ((PH) < 11 ? 6 : 0)) : "memory");    \
    __builtin_amdgcn_s_barrier();                                           \
    { const char* wb = (const char*)smem + ((PH) & 1) * 49152;              \
      const char* ib = (const char*)smem + 98304 + (cq_ & 1) * 24576;       \
      __builtin_amdgcn_s_setprio(1);                                        \
      _Pragma("unroll")                                                     \
      for (int s = 0; s < 3; ++s) {                                         \
          bf16x8 a[4], b[7];                                                \
          _Pragma("unroll")                                                 \
          for (int m = 0; m < 4; ++m)                                       \
              a[m] = *(const bf16x8*)(wb + albase + s * 16384 + m * 256);   \
          _Pragma("unroll")                                                 \
          for (int nf = 0; nf < 7; ++nf)                                    \
              b[nf] = *(const bf16x8*)(ib + rowoff[nf] + (r_ * 58 + s) * 16); \
          _Pragma("unroll")                                                 \
          for (int m = 0; m < 4; ++m)                                       \
              _Pragma("unroll")                                             \
              for (int nf = 0; nf < 7; ++nf)                                \
                  acc[m][nf] = __builtin_amdgcn_mfma_f32_16x16x32_bf16(     \
                      a[m], b[nf], acc[m][nf], 0, 0, 0);                    \
      }                                                                     \
      __builtin_amdgcn_s_setprio(0);                                        \
    }                                                                       \
    __builtin_amdgcn_s_barrier();                                           \
} while (0)

    PHASE(0);  PHASE(1);  PHASE(2);  PHASE(3);
    PHASE(4);  PHASE(5);  PHASE(6);  PHASE(7);
    PHASE(8);  PHASE(9);  PHASE(10); PHASE(11);

#undef PHASE
#undef STAGE_I
#undef STAGE_W

    // epilogue: D col = l15 (pixel), row = lk*4 + j (ko)
    const int sp0 = rb * 56 + wpx;                 // block pixel base in image
#pragma unroll
    for (int m = 0; m < 4; ++m) {
        int kb = wko + m * 16 + lk * 4;            // absolute ko
        f32x4 bs = *(const f32x4*)(bias + kb);
#pragma unroll
        for (int nf = 0; nf < 7; ++nf) {
            float* ob = out + ((size_t)(n * K_OUT + kb) * IMG) + sp0 + nf * 16 + l15;
#pragma unroll
            for (int j = 0; j < 4; ++j)
                ob[(size_t)j * IMG] = acc[m][nf][j] + bs[j];
        }
    }
}

// ---- fallback (only if ws too small): naive fp32 direct conv ----
__global__ void conv_naive(const float* __restrict__ inp,
                           const float* __restrict__ ker,
                           const float* __restrict__ bias,
                           float* __restrict__ out, int total) {
    int o = blockIdx.x * blockDim.x + threadIdx.x;
    if (o >= total) return;
    int x = o % HW, y = (o / HW) % HW, ko = (o / IMG) % K_OUT, n = o / (IMG * K_OUT);
    float acc = bias[ko];
    for (int c = 0; c < C_IN; ++c)
        for (int r = 0; r < 3; ++r) {
            int iy = y + r - 1; if ((unsigned)iy >= HW) continue;
            for (int s = 0; s < 3; ++s) {
                int ix = x + s - 1; if ((unsigned)ix >= HW) continue;
                acc += inp[((n * C_IN + c) * HW + iy) * HW + ix]
                     * ker[((ko * C_IN + c) * 3 + r) * 3 + s];
            }
        }
    out[o] = acc;
}

extern "C" void kernel_launch(void* const* d_in, const int* in_sizes, int n_in,
                              void* d_out, int out_size, void* d_ws, size_t ws_size,
                              hipStream_t stream) {
    const float* inp  = (const float*)d_in[0];
    const float* ker  = (const float*)d_in[1];
    const float* bias = (const float*)d_in[2];
    float* out = (float*)d_out;

    const size_t need = (size_t)PADTOT * 2 + (size_t)K_OUT * KTOT * 2;
    if (ws_size < need) {
        int total = NBATCH * K_OUT * IMG;
        conv_naive<<<(total + 255) / 256, 256, 0, stream>>>(inp, ker, bias, out, total);
        return;
    }

    unsigned short* inb = (unsigned short*)d_ws;
    unsigned short* wtb = inb + (size_t)PADTOT;

    prep_input<<<NBATCH * PW, 256, 0, stream>>>(inp, inb);
    prep_weights<<<(K_OUT * KTOT) / 256, 256, 0, stream>>>(ker, wtb);

    conv_mfma<<<448, 512, 0, stream>>>(inb, wtb, bias, out);
}

// Round 9
// 83.531 us; speedup vs baseline: 1.4476x; 1.0241x over previous
//
#include <hip/hip_runtime.h>
#include <hip/hip_bf16.h>

// Conv2d 3x3 s1 p1, NCHW/OIHW fp32 -> fp32. bf16 implicit GEMM with
// conv-aware LDS reuse. R8: superbank-aware chunk permutation — every wave's
// ds_read_b128 covers 1024 contiguous LDS bytes (32x32B superbanks).
// weights [s][koq][cc][kor], input [t][Xq][cc][Xr] (X padded to 64).
// Staging is a pure linear slab copy from identically-laid-out global ws.

#define C_IN   128
#define K_OUT  256
#define HW     56
#define IMG    3136
#define NBATCH 32
#define PW     58
#define KTOT   1152
// input ws: [cq:4][n:32][py:58][Xq:4][cc:4][Xr:16] chunks of 16B
#define IN_WS_USHORT ((size_t)4*NBATCH*PW*256*8)     // 15,204,352 ushorts
#define WT_WS_USHORT ((size_t)12*3072*8)             // 294,912 ushorts

typedef __bf16 bf16x8 __attribute__((ext_vector_type(8)));
typedef float  f32x4  __attribute__((ext_vector_type(4)));
typedef unsigned short ushort8 __attribute__((ext_vector_type(8)));

__device__ inline unsigned short f2bf(float f) {
    unsigned int u = __builtin_bit_cast(unsigned int, f);
    u += ((u >> 16) & 1u) + 0x7FFFu;   // RNE
    return (unsigned short)(u >> 16);
}

__device__ __forceinline__ void gl2lds16(const unsigned short* g, unsigned short* l) {
    __builtin_amdgcn_global_load_lds(
        (const __attribute__((address_space(1))) unsigned int*)g,
        (__attribute__((address_space(3))) unsigned int*)l, 16, 0, 0);
}

// ---- prep A: NCHW fp32 -> [cq][n][py][Xq][cc][Xr][8c] bf16 ----
__global__ void prep_input(const float* __restrict__ inp,
                           unsigned short* __restrict__ dst) {
    __shared__ unsigned short tile[C_IN * 57];   // [c][x], stride 57
    int n = blockIdx.x / PW, py = blockIdx.x % PW;
    ushort8* d8 = (ushort8*)dst;
    const bool border = (py == 0 || py == PW - 1);
    if (!border) {
        const float* src = inp + (size_t)n * C_IN * IMG + (py - 1) * HW;
        for (int i = threadIdx.x; i < C_IN * HW; i += 256) {
            int c = i / HW, x = i - c * HW;      // coalesced read along x
            tile[c * 57 + x] = f2bf(src[c * IMG + x]);
        }
        __syncthreads();
    }
    for (int i = threadIdx.x; i < 1024; i += 256) {     // 4 cq x 256 chunks
        int cq = i >> 8, rem = i & 255;
        int X = ((rem >> 6) & 3) * 16 + (rem & 15);
        int cc = (rem >> 4) & 3;
        ushort8 v = (ushort8)0;
        if (!border && X >= 1 && X <= HW) {
#pragma unroll
            for (int e = 0; e < 8; ++e)
                v[e] = tile[(cq * 32 + cc * 8 + e) * 57 + (X - 1)];
        }
        d8[((size_t)(cq * NBATCH + n) * PW + py) * 256 + rem] = v;
    }
}

// ---- prep B: OIHW fp32 -> 12 panels [p=cq*3+r][s][koq][cc][kor][8c] bf16 ----
__global__ void prep_weights(const float* __restrict__ w,
                             unsigned short* __restrict__ dst) {
    int idx = blockIdx.x * 256 + threadIdx.x;    // 0..294911
    int chunk = idx >> 3, e = idx & 7;
    int p = chunk / 3072, rem = chunk - p * 3072;
    int s = rem >> 10, rem2 = rem & 1023;
    int koq = rem2 >> 6, cc = (rem2 >> 4) & 3, kor = rem2 & 15;
    int ko = koq * 16 + kor;
    int cq = p / 3, r = p - 3 * cq;
    int c = cq * 32 + cc * 8 + e;
    dst[idx] = f2bf(w[(ko * C_IN + c) * 9 + r * 3 + s]);
}

// ---- main conv ----
// LDS (bytes): wslot0 [0,48K) wslot1 [48K,96K) islot0 [96K,120K) islot1 [120K,144K)
// wslot chunks (16B): [3 s][16 koq][4 cc][16 kor]
// islot chunks:       [6 t][4 Xq][4 cc][16 Xr]
__global__ __launch_bounds__(512, 2) void conv_mfma(
        const unsigned short* __restrict__ In,
        const unsigned short* __restrict__ Wt,
        const float* __restrict__ bias,
        float* __restrict__ out) {
    __shared__ unsigned short smem[73728];

    const int tid = threadIdx.x;
    const int lane = tid & 63, wv = tid >> 6;
    const int l15 = lane & 15, lk = lane >> 4;
    const int blk = blockIdx.x;
    const int n = blk / 14, rb = (blk % 14) * 4;   // first image row of block

    const int wko = (wv & 3) * 64;                 // wave ko base
    const int wpx = (wv >> 2) * 112;               // wave px base (local)
    const int albase = (wv & 3) * 4096 + lk * 256 + l15 * 16;  // A lane byte off

    int addrB[3][7];                               // B lane byte offsets (r=0)
#pragma unroll
    for (int nf = 0; nf < 7; ++nf) {
        int p = wpx + nf * 16 + l15;               // local pixel 0..223
        int yl = p / 56, x = p - yl * 56;
#pragma unroll
        for (int s = 0; s < 3; ++s) {
            int X = x + s;
            addrB[s][nf] = yl * 4096 + (X >> 4) * 1024 + lk * 256 + (X & 15) * 16;
        }
    }

    f32x4 acc[4][7];
#pragma unroll
    for (int m = 0; m < 4; ++m)
#pragma unroll
        for (int nf = 0; nf < 7; ++nf) acc[m][nf] = (f32x4)0.0f;

#define STAGE_W(PHN) do {                                                   \
    _Pragma("unroll")                                                       \
    for (int li = 0; li < 6; ++li) {                                        \
        int chunk = li * 512 + tid;                                         \
        gl2lds16(Wt + (PHN) * 24576 + chunk * 8,                            \
                 &smem[((PHN) & 1) * 24576 + chunk * 8]);                   \
    } } while (0)

#define STAGE_I(CQN, R_) do {                                               \
    int chunk = (R_) * 512 + tid;                                           \
    gl2lds16(In + ((size_t)((CQN) * NBATCH + n) * PW + rb) * 2048 + chunk * 8, \
             &smem[49152 + ((CQN) & 1) * 12288 + chunk * 8]);               \
} while (0)

    // prologue: weights panel 0, input c-quarter 0
    STAGE_W(0);
    STAGE_I(0, 0); STAGE_I(0, 1); STAGE_I(0, 2);

#define PHASE(PH) do {                                                      \
    constexpr int cq_ = (PH) / 3, r_ = (PH) % 3;                            \
    if ((PH) < 11) { STAGE_W((PH) + 1); }                                   \
    if (cq_ < 3)   { STAGE_I(cq_ + 1, r_); }                                \
    asm volatile("s_waitcnt vmcnt(%0)"                                      \
                 :: "i"((PH) < 9 ? 7 : ((PH) < 11 ? 6 : 0)) : "memory");    \
    __builtin_amdgcn_s_barrier();                                           \
    { const char* wb = (const char*)smem + ((PH) & 1) * 49152;              \
      const char* ib = (const char*)smem + 98304 + (cq_ & 1) * 24576;       \
      __builtin_amdgcn_s_setprio(1);                                        \
      _Pragma("unroll")                                                     \
      for (int s = 0; s < 3; ++s) {                                         \
          bf16x8 a[4], b[7];                                                \
          _Pragma("unroll")                                                 \
          for (int m = 0; m < 4; ++m)                                       \
              a[m] = *(const bf16x8*)(wb + albase + s * 16384 + m * 1024);  \
          _Pragma("unroll")                                                 \
          for (int nf = 0; nf < 7; ++nf)                                    \
              b[nf] = *(const bf16x8*)(ib + addrB[s][nf] + r_ * 4096);      \
          _Pragma("unroll")                                                 \
          for (int m = 0; m < 4; ++m)                                       \
              _Pragma("unroll")                                             \
              for (int nf = 0; nf < 7; ++nf)                                \
                  acc[m][nf] = __builtin_amdgcn_mfma_f32_16x16x32_bf16(     \
                      a[m], b[nf], acc[m][nf], 0, 0, 0);                    \
      }                                                                     \
      __builtin_amdgcn_s_setprio(0);                                        \
    }                                                                       \
    __builtin_amdgcn_s_barrier();                                           \
} while (0)

    PHASE(0);  PHASE(1);  PHASE(2);  PHASE(3);
    PHASE(4);  PHASE(5);  PHASE(6);  PHASE(7);
    PHASE(8);  PHASE(9);  PHASE(10); PHASE(11);

#undef PHASE
#undef STAGE_I
#undef STAGE_W

    // epilogue: D col = l15 (pixel), row = lk*4 + j (ko)
    const int sp0 = rb * 56 + wpx;                 // block pixel base in image
#pragma unroll
    for (int m = 0; m < 4; ++m) {
        int kb = wko + m * 16 + lk * 4;            // absolute ko
        f32x4 bs = *(const f32x4*)(bias + kb);
#pragma unroll
        for (int nf = 0; nf < 7; ++nf) {
            float* ob = out + ((size_t)(n * K_OUT + kb) * IMG) + sp0 + nf * 16 + l15;
#pragma unroll
            for (int j = 0; j < 4; ++j)
                ob[(size_t)j * IMG] = acc[m][nf][j] + bs[j];
        }
    }
}

// ---- fallback (only if ws too small): naive fp32 direct conv ----
__global__ void conv_naive(const float* __restrict__ inp,
                           const float* __restrict__ ker,
                           const float* __restrict__ bias,
                           float* __restrict__ out, int total) {
    int o = blockIdx.x * blockDim.x + threadIdx.x;
    if (o >= total) return;
    int x = o % HW, y = (o / HW) % HW, ko = (o / IMG) % K_OUT, n = o / (IMG * K_OUT);
    float acc = bias[ko];
    for (int c = 0; c < C_IN; ++c)
        for (int r = 0; r < 3; ++r) {
            int iy = y + r - 1; if ((unsigned)iy >= HW) continue;
            for (int s = 0; s < 3; ++s) {
                int ix = x + s - 1; if ((unsigned)ix >= HW) continue;
                acc += inp[((n * C_IN + c) * HW + iy) * HW + ix]
                     * ker[((ko * C_IN + c) * 3 + r) * 3 + s];
            }
        }
    out[o] = acc;
}

extern "C" void kernel_launch(void* const* d_in, const int* in_sizes, int n_in,
                              void* d_out, int out_size, void* d_ws, size_t ws_size,
                              hipStream_t stream) {
    const float* inp  = (const float*)d_in[0];
    const float* ker  = (const float*)d_in[1];
    const float* bias = (const float*)d_in[2];
    float* out = (float*)d_out;

    const size_t need = (IN_WS_USHORT + WT_WS_USHORT) * 2;
    if (ws_size < need) {
        int total = NBATCH * K_OUT * IMG;
        conv_naive<<<(total + 255) / 256, 256, 0, stream>>>(inp, ker, bias, out, total);
        return;
    }

    unsigned short* inb = (unsigned short*)d_ws;
    unsigned short* wtb = inb + IN_WS_USHORT;

    prep_input<<<NBATCH * PW, 256, 0, stream>>>(inp, inb);
    prep_weights<<<(K_OUT * KTOT) / 256, 256, 0, stream>>>(ker, wtb);

    conv_mfma<<<448, 512, 0, stream>>>(inb, wtb, bias, out);
}

// Round 10
// 81.149 us; speedup vs baseline: 1.4901x; 1.0294x over previous
//
#include <hip/hip_runtime.h>
#include <hip/hip_bf16.h>

// Conv2d 3x3 s1 p1, NCHW/OIHW fp32 -> fp32. bf16 implicit GEMM.
// R9: 128ko x 224px blocks, 80KB LDS (W dbuf 48K + 8-slot input row ring 32K)
// -> 2 independent blocks/CU to hide staging latency. Superbank-clean reads.

#define C_IN   128
#define K_OUT  256
#define HW     56
#define IMG    3136
#define NBATCH 32
#define PW     58
#define KTOT   1152
#define IN_WS_USHORT ((size_t)4*NBATCH*PW*256*8)     // [cq][n][py][256ch][8]
#define WT_WS_USHORT ((size_t)12*2*1536*8)           // [p][koh][1536ch][8]

typedef __bf16 bf16x8 __attribute__((ext_vector_type(8)));
typedef float  f32x4  __attribute__((ext_vector_type(4)));
typedef unsigned short ushort8 __attribute__((ext_vector_type(8)));

__device__ inline unsigned short f2bf(float f) {
    unsigned int u = __builtin_bit_cast(unsigned int, f);
    u += ((u >> 16) & 1u) + 0x7FFFu;   // RNE
    return (unsigned short)(u >> 16);
}

__device__ __forceinline__ void gl2lds16(const unsigned short* g, unsigned short* l) {
    __builtin_amdgcn_global_load_lds(
        (const __attribute__((address_space(1))) unsigned int*)g,
        (__attribute__((address_space(3))) unsigned int*)l, 16, 0, 0);
}

// ---- prep A: NCHW fp32 -> [cq][n][py][Xq:4][cc:4][Xr:16][8c] bf16 ----
__global__ void prep_input(const float* __restrict__ inp,
                           unsigned short* __restrict__ dst) {
    __shared__ unsigned short tile[C_IN * 57];   // [c][x], stride 57
    int n = blockIdx.x / PW, py = blockIdx.x % PW;
    ushort8* d8 = (ushort8*)dst;
    const bool border = (py == 0 || py == PW - 1);
    if (!border) {
        const float* src = inp + (size_t)n * C_IN * IMG + (py - 1) * HW;
        for (int i = threadIdx.x; i < C_IN * HW; i += 256) {
            int c = i / HW, x = i - c * HW;      // coalesced read along x
            tile[c * 57 + x] = f2bf(src[c * IMG + x]);
        }
        __syncthreads();
    }
    for (int i = threadIdx.x; i < 1024; i += 256) {     // 4 cq x 256 chunks
        int cq = i >> 8, rem = i & 255;
        int X = ((rem >> 6) & 3) * 16 + (rem & 15);
        int cc = (rem >> 4) & 3;
        ushort8 v = (ushort8)0;
        if (!border && X >= 1 && X <= HW) {
#pragma unroll
            for (int e = 0; e < 8; ++e)
                v[e] = tile[(cq * 32 + cc * 8 + e) * 57 + (X - 1)];
        }
        d8[((size_t)(cq * NBATCH + n) * PW + py) * 256 + rem] = v;
    }
}

// ---- prep B: OIHW fp32 -> [p=cq*3+r][koh:2][s:3][koq:8][cc:4][kor:16][8c] ----
__global__ void prep_weights(const float* __restrict__ w,
                             unsigned short* __restrict__ dst) {
    int idx = blockIdx.x * 256 + threadIdx.x;    // 0..589823
    int chunk = idx >> 3, e = idx & 7;
    int p = chunk / 3072, rem = chunk - p * 3072;
    int koh = rem / 1536, rem2 = rem - koh * 1536;
    int s = rem2 / 512, rem3 = rem2 - s * 512;
    int koq = rem3 >> 6, cc = (rem3 >> 4) & 3, kor = rem3 & 15;
    int ko = koh * 128 + koq * 16 + kor;
    int cq = p / 3, r = p - 3 * cq;
    int c = cq * 32 + cc * 8 + e;
    dst[idx] = f2bf(w[(ko * C_IN + c) * 9 + r * 3 + s]);
}

// ---- main conv ----
// LDS bytes: wslot0 [0,24576) wslot1 [24576,49152) ring [49152,81920)
// wslot chunks (16B): [3 s][8 koq][4 cc][16 kor]
// ring: 8 slots x 4KB, slot(c,t) = (6c+t)&7; row = [4 Xq][4 cc][16 Xr]
__global__ __launch_bounds__(256, 2) void conv_mfma(
        const unsigned short* __restrict__ In,
        const unsigned short* __restrict__ Wt,
        const float* __restrict__ bias,
        float* __restrict__ out) {
    __shared__ unsigned short smem[40960];       // 81920 B

    const int tid = threadIdx.x;
    const int lane = tid & 63, wv = tid >> 6;
    const int l15 = lane & 15, lk = lane >> 4;
    const int koh = blockIdx.x;
    const int by = blockIdx.y;
    const int n = by / 14, rb = (by % 14) * 4;

    const int wkol = (wv & 1) * 64;                // wave ko base (in block)
    const int wpx  = (wv >> 1) * 112;              // wave px base (local)
    const int albase = (wv & 1) * 4096 + lk * 256 + l15 * 16;

    int yl[7], xp[3][7];
#pragma unroll
    for (int nf = 0; nf < 7; ++nf) {
        int p = wpx + nf * 16 + l15;               // local pixel 0..223
        yl[nf] = p / 56;
        int x = p - yl[nf] * 56;
#pragma unroll
        for (int s = 0; s < 3; ++s) {
            int X = x + s;
            xp[s][nf] = ((X >> 4) << 10) + lk * 256 + ((X & 15) << 4);
        }
    }

    f32x4 acc[4][7];
#pragma unroll
    for (int m = 0; m < 4; ++m)
#pragma unroll
        for (int nf = 0; nf < 7; ++nf) acc[m][nf] = (f32x4)0.0f;

#define STAGE_W(PHN) do {                                                   \
    _Pragma("unroll")                                                       \
    for (int li = 0; li < 6; ++li) {                                        \
        int chunk = li * 256 + tid;                                         \
        gl2lds16(Wt + ((size_t)((PHN) * 2 + koh)) * 12288 + chunk * 8,      \
                 &smem[((PHN) & 1) * 12288 + chunk * 8]);                   \
    } } while (0)

#define STAGE_ROW(C_, T_) do {                                              \
    gl2lds16(In + ((size_t)(((C_) * NBATCH + n) * PW + rb + (T_))) * 2048 + tid * 8, \
             &smem[24576 + ((6 * (C_) + (T_)) & 7) * 2048 + tid * 8]);      \
} while (0)

    // prologue: W panel 0 + input rows c0 t0..3
    STAGE_W(0);
    STAGE_ROW(0, 0); STAGE_ROW(0, 1); STAGE_ROW(0, 2); STAGE_ROW(0, 3);

#define PHASE(PH) do {                                                      \
    constexpr int cq_ = (PH) / 3, r_ = (PH) % 3;                            \
    if ((PH) < 11) STAGE_W((PH) + 1);                                       \
    if constexpr (r_ == 0) {                                                \
        if constexpr (cq_ < 3) { STAGE_ROW(cq_ + 1, 0); STAGE_ROW(cq_ + 1, 1); } \
        STAGE_ROW(cq_, 4);                                                  \
    } else if constexpr (r_ == 1) {                                         \
        if constexpr (cq_ < 3) STAGE_ROW(cq_ + 1, 2);                       \
        STAGE_ROW(cq_, 5);                                                  \
    } else {                                                                \
        if constexpr (cq_ < 3) STAGE_ROW(cq_ + 1, 3);                       \
    }                                                                       \
    { constexpr int nIss = ((PH) < 11 ? 6 : 0) +                            \
          (r_ == 0 ? (cq_ < 3 ? 3 : 1) : r_ == 1 ? (cq_ < 3 ? 2 : 1)        \
                                       : (cq_ < 3 ? 1 : 0));                \
      asm volatile("s_waitcnt vmcnt(%0)" :: "i"(nIss) : "memory"); }        \
    __builtin_amdgcn_s_barrier();                                           \
    { const char* wb = (const char*)smem + ((PH) & 1) * 24576;              \
      const char* ib = (const char*)smem + 49152;                           \
      int roff[7];                                                          \
      _Pragma("unroll")                                                     \
      for (int nf = 0; nf < 7; ++nf)                                        \
          roff[nf] = ((6 * cq_ + r_ + yl[nf]) & 7) << 12;                   \
      __builtin_amdgcn_s_setprio(1);                                        \
      _Pragma("unroll")                                                     \
      for (int s = 0; s < 3; ++s) {                                         \
          bf16x8 a[4], b[7];                                                \
          _Pragma("unroll")                                                 \
          for (int m = 0; m < 4; ++m)                                       \
              a[m] = *(const bf16x8*)(wb + albase + s * 8192 + m * 1024);   \
          _Pragma("unroll")                                                 \
          for (int nf = 0; nf < 7; ++nf)                                    \
              b[nf] = *(const bf16x8*)(ib + roff[nf] + xp[s][nf]);          \
          _Pragma("unroll")                                                 \
          for (int m = 0; m < 4; ++m)                                       \
              _Pragma("unroll")                                             \
              for (int nf = 0; nf < 7; ++nf)                                \
                  acc[m][nf] = __builtin_amdgcn_mfma_f32_16x16x32_bf16(     \
                      a[m], b[nf], acc[m][nf], 0, 0, 0);                    \
      }                                                                     \
      __builtin_amdgcn_s_setprio(0);                                        \
    }                                                                       \
    __builtin_amdgcn_s_barrier();                                           \
} while (0)

    PHASE(0);  PHASE(1);  PHASE(2);  PHASE(3);
    PHASE(4);  PHASE(5);  PHASE(6);  PHASE(7);
    PHASE(8);  PHASE(9);  PHASE(10); PHASE(11);

#undef PHASE
#undef STAGE_ROW
#undef STAGE_W

    // epilogue: D col = l15 (pixel), row = lk*4 + j (ko)
    const int sp0 = rb * 56 + wpx;
#pragma unroll
    for (int m = 0; m < 4; ++m) {
        int kb = koh * 128 + wkol + m * 16 + lk * 4;
        f32x4 bs = *(const f32x4*)(bias + kb);
#pragma unroll
        for (int nf = 0; nf < 7; ++nf) {
            float* ob = out + ((size_t)(n * K_OUT + kb) * IMG) + sp0 + nf * 16 + l15;
#pragma unroll
            for (int j = 0; j < 4; ++j)
                ob[(size_t)j * IMG] = acc[m][nf][j] + bs[j];
        }
    }
}

// ---- fallback (only if ws too small): naive fp32 direct conv ----
__global__ void conv_naive(const float* __restrict__ inp,
                           const float* __restrict__ ker,
                           const float* __restrict__ bias,
                           float* __restrict__ out, int total) {
    int o = blockIdx.x * blockDim.x + threadIdx.x;
    if (o >= total) return;
    int x = o % HW, y = (o / HW) % HW, ko = (o / IMG) % K_OUT, n = o / (IMG * K_OUT);
    float acc = bias[ko];
    for (int c = 0; c < C_IN; ++c)
        for (int r = 0; r < 3; ++r) {
            int iy = y + r - 1; if ((unsigned)iy >= HW) continue;
            for (int s = 0; s < 3; ++s) {
                int ix = x + s - 1; if ((unsigned)ix >= HW) continue;
                acc += inp[((n * C_IN + c) * HW + iy) * HW + ix]
                     * ker[((ko * C_IN + c) * 3 + r) * 3 + s];
            }
        }
    out[o] = acc;
}

extern "C" void kernel_launch(void* const* d_in, const int* in_sizes, int n_in,
                              void* d_out, int out_size, void* d_ws, size_t ws_size,
                              hipStream_t stream) {
    const float* inp  = (const float*)d_in[0];
    const float* ker  = (const float*)d_in[1];
    const float* bias = (const float*)d_in[2];
    float* out = (float*)d_out;

    const size_t need = (IN_WS_USHORT + WT_WS_USHORT) * 2;
    if (ws_size < need) {
        int total = NBATCH * K_OUT * IMG;
        conv_naive<<<(total + 255) / 256, 256, 0, stream>>>(inp, ker, bias, out, total);
        return;
    }

    unsigned short* inb = (unsigned short*)d_ws;
    unsigned short* wtb = inb + IN_WS_USHORT;

    prep_input<<<NBATCH * PW, 256, 0, stream>>>(inp, inb);
    prep_weights<<<(int)(WT_WS_USHORT / 256), 256, 0, stream>>>(ker, wtb);

    conv_mfma<<<dim3(2, 448), 256, 0, stream>>>(inb, wtb, bias, out);
}